// Round 4
// baseline (1055.167 us; speedup 1.0000x reference)
//
#include <hip/hip_runtime.h>

typedef unsigned short u16;
typedef unsigned int u32;
typedef unsigned long long u64;

#define T_TOK 8192
#define DIM 768
#define FF 3072
#define NE 8
#define CAP 2560
#define LSTR 5120
#define MAXMT 20

typedef __attribute__((ext_vector_type(8))) short s8v;
typedef __attribute__((ext_vector_type(4))) float f4v;

__device__ __forceinline__ u16 f2bf(float f) {
  union { float f; u32 u; } v; v.f = f;
  u32 r = v.u + 0x7FFFu + ((v.u >> 16) & 1u);
  return (u16)(r >> 16);
}

__device__ __forceinline__ void glds16(const void* g, void* l) {
  __builtin_amdgcn_global_load_lds(
      (const __attribute__((address_space(1))) u32*)g,
      (__attribute__((address_space(3))) u32*)l, 16, 0, 0);
}

// ---------------- cast fp32 -> bf16, 8 elems/thread ----------------
__global__ void cast_bf16_kernel(const float* __restrict__ src, u16* __restrict__ dst, int n8) {
  int i = blockIdx.x * blockDim.x + threadIdx.x;
  if (i >= n8) return;
  const float4* s4 = (const float4*)src;
  float4 a = s4[2 * i], b = s4[2 * i + 1];
  uint4 o;
  o.x = (u32)f2bf(a.x) | ((u32)f2bf(a.y) << 16);
  o.y = (u32)f2bf(a.z) | ((u32)f2bf(a.w) << 16);
  o.z = (u32)f2bf(b.x) | ((u32)f2bf(b.y) << 16);
  o.w = (u32)f2bf(b.z) | ((u32)f2bf(b.w) << 16);
  ((uint4*)dst)[i] = o;
}

// cast three equal-size weight tensors in one launch
__global__ void cast3_bf16_kernel(const float* __restrict__ s0, const float* __restrict__ s1,
                                  const float* __restrict__ s2, u16* __restrict__ d0,
                                  u16* __restrict__ d1, u16* __restrict__ d2, int n8) {
  int i = blockIdx.x * blockDim.x + threadIdx.x;
  if (i >= n8) return;
  const float* src = (blockIdx.y == 0) ? s0 : (blockIdx.y == 1) ? s1 : s2;
  u16* dst = (blockIdx.y == 0) ? d0 : (blockIdx.y == 1) ? d1 : d2;
  const float4* s4 = (const float4*)src;
  float4 a = s4[2 * i], b = s4[2 * i + 1];
  uint4 o;
  o.x = (u32)f2bf(a.x) | ((u32)f2bf(a.y) << 16);
  o.y = (u32)f2bf(a.z) | ((u32)f2bf(a.w) << 16);
  o.z = (u32)f2bf(b.x) | ((u32)f2bf(b.y) << 16);
  o.w = (u32)f2bf(b.z) | ((u32)f2bf(b.w) << 16);
  ((uint4*)dst)[i] = o;
}

// ---------------- router: one wave per token, NO atomics ----------------
__global__ __launch_bounds__(256) void router_kernel(
    const float* __restrict__ x, const float* __restrict__ wg,
    int* __restrict__ tki, float* __restrict__ tkp,
    float* __restrict__ probs, float* __restrict__ lse2) {
  int lane = threadIdx.x & 63;
  int t = blockIdx.x * 4 + (threadIdx.x >> 6);
  const float* xr = x + (long)t * DIM;
  float acc[NE];
#pragma unroll
  for (int e = 0; e < NE; e++) acc[e] = 0.f;
  for (int i = 0; i < DIM / 64; i++) {
    float xv = xr[lane + 64 * i];
#pragma unroll
    for (int e = 0; e < NE; e++) acc[e] += xv * wg[e * DIM + lane + 64 * i];
  }
#pragma unroll
  for (int off = 32; off > 0; off >>= 1) {
#pragma unroll
    for (int e = 0; e < NE; e++) acc[e] += __shfl_xor(acc[e], off);
  }
  if (lane == 0) {
    float m = acc[0];
#pragma unroll
    for (int e = 1; e < NE; e++) m = fmaxf(m, acc[e]);
    float p[NE], s = 0.f;
#pragma unroll
    for (int e = 0; e < NE; e++) { p[e] = __expf(acc[e] - m); s += p[e]; }
    float inv = 1.f / s;
    int e0 = 0;
#pragma unroll
    for (int e = 1; e < NE; e++) if (acc[e] > acc[e0]) e0 = e;
    int e1 = (e0 == 0) ? 1 : 0;
#pragma unroll
    for (int e = 0; e < NE; e++) if (e != e0 && acc[e] > acc[e1]) e1 = e;
    float p0 = p[e0] * inv, p1 = p[e1] * inv;
    float rn = 1.f / (p0 + p1);
    tki[2 * t] = e0; tki[2 * t + 1] = e1;
    tkp[2 * t] = p0 * rn; tkp[2 * t + 1] = p1 * rn;
    float4 pa = {p[0] * inv, p[1] * inv, p[2] * inv, p[3] * inv};
    float4 pb = {p[4] * inv, p[5] * inv, p[6] * inv, p[7] * inv};
    ((float4*)(probs + t * 8))[0] = pa;
    ((float4*)(probs + t * 8))[1] = pb;
    float lse = __logf(s) + m;
    lse2[t] = lse * lse;
  }
}

// ---------------- reduce router stats: few atomics total ----------------
__global__ __launch_bounds__(1024) void reduce_router_kernel(
    const int* __restrict__ tki, const float* __restrict__ probs, const float* __restrict__ lse2,
    int* __restrict__ fcnt, float* __restrict__ psum, float* __restrict__ zsum) {
  int t = blockIdx.x * 1024 + threadIdx.x;
  float4 pa = ((const float4*)(probs + t * 8))[0];
  float4 pb = ((const float4*)(probs + t * 8))[1];
  float p[8] = {pa.x, pa.y, pa.z, pa.w, pb.x, pb.y, pb.z, pb.w};
  float z = lse2[t];
  int e0 = tki[2 * t], e1 = tki[2 * t + 1];
  int fc[8];
#pragma unroll
  for (int e = 0; e < 8; e++) fc[e] = (e0 == e ? 1 : 0) + (e1 == e ? 1 : 0);
#pragma unroll
  for (int off = 32; off > 0; off >>= 1) {
#pragma unroll
    for (int e = 0; e < 8; e++) { p[e] += __shfl_xor(p[e], off); fc[e] += __shfl_xor(fc[e], off); }
    z += __shfl_xor(z, off);
  }
  __shared__ float sp[16][9];
  __shared__ int sf[16][8];
  int wv = threadIdx.x >> 6, lane = threadIdx.x & 63;
  if (lane == 0) {
#pragma unroll
    for (int e = 0; e < 8; e++) { sp[wv][e] = p[e]; sf[wv][e] = fc[e]; }
    sp[wv][8] = z;
  }
  __syncthreads();
  if (threadIdx.x < 9) {
    float s = 0.f;
    for (int w = 0; w < 16; w++) s += sp[w][threadIdx.x];
    if (threadIdx.x < 8) atomicAdd(&psum[threadIdx.x], s);
    else atomicAdd(zsum, s);
  }
  if (threadIdx.x >= 64 && threadIdx.x < 72) {
    int e = threadIdx.x - 64;
    int s = 0;
    for (int w = 0; w < 16; w++) s += sf[w][e];
    atomicAdd(&fcnt[e], s);
  }
}

// ---------------- rank + dispatch (exact capacity semantics) ----------------
__global__ __launch_bounds__(1024) void rank_dispatch_kernel(
    const int* __restrict__ tki, const float* __restrict__ tkp,
    int* __restrict__ ltk, float* __restrict__ lw,
    int* __restrict__ counts, int* __restrict__ baserow) {
  __shared__ int wave_cnt[2][16][8];
  __shared__ int base[2][8];
  __shared__ int epos[8];
  int tid = threadIdx.x, wv = tid >> 6, lane = tid & 63;
  if (tid < 16) base[tid >> 3][tid & 7] = 0;
  if (tid < 8) epos[tid] = 0;
  __syncthreads();
  u64 lmask = (lane == 63) ? 0x7FFFFFFFFFFFFFFFull : ((1ull << lane) - 1ull);
  for (int c = 0; c < T_TOK / 1024; c++) {
    int t = c * 1024 + tid;
    int e0 = tki[2 * t], e1 = tki[2 * t + 1];
    float p0 = tkp[2 * t], p1 = tkp[2 * t + 1];
    int pre0 = 0, pre1 = 0;
    for (int e = 0; e < 8; e++) {
      u64 m0 = __ballot(e0 == e);
      if (e0 == e) pre0 = __popcll(m0 & lmask);
      if (lane == 0) wave_cnt[0][wv][e] = __popcll(m0);
      u64 m1 = __ballot(e1 == e);
      if (e1 == e) pre1 = __popcll(m1 & lmask);
      if (lane == 0) wave_cnt[1][wv][e] = __popcll(m1);
    }
    __syncthreads();
    if (tid < 16) {
      int k = tid >> 3, e = tid & 7;
      int run = base[k][e];
      for (int w = 0; w < 16; w++) {
        int v = wave_cnt[k][w][e];
        wave_cnt[k][w][e] = run;
        run += v;
      }
      base[k][e] = run;
    }
    __syncthreads();
    int r0 = wave_cnt[0][wv][e0] + pre0;
    int r1 = wave_cnt[1][wv][e1] + pre1;
    if (r0 < CAP) { int p = atomicAdd(&epos[e0], 1); ltk[e0 * LSTR + p] = (t << 1); lw[e0 * LSTR + p] = p0; }
    if (r1 < CAP) { int p = atomicAdd(&epos[e1], 1); ltk[e1 * LSTR + p] = (t << 1) | 1; lw[e1 * LSTR + p] = p1; }
    __syncthreads();
  }
  if (tid == 0) {
    int run = 0;
    for (int e = 0; e < 8; e++) { counts[e] = epos[e]; baserow[e] = run; run += epos[e]; }
  }
}

// ---------------- GEMM1: H = silu(x@Wg^T)*(x@Wu^T) ----------------
// A (gathered tokens) staged in LDS fragment-major (conflict-free); W frags direct global->VGPR.
__global__ __launch_bounds__(256, 2) void gemm1_kernel(
    const u16* __restrict__ xb, const u16* __restrict__ wgb, const u16* __restrict__ wub,
    u16* __restrict__ H, const int* __restrict__ counts, const int* __restrict__ baserow,
    const int* __restrict__ ltk) {
  int id = blockIdx.x;
  int xcd = id & 7;
  int q = id >> 3;
  int gg = q / MAXMT;
  int mt = q - gg * MAXMT;
  int g = gg * 8 + xcd;
  int e = g / 48;
  int nt = g - e * 48;
  int cnt = counts[e];
  if (mt * 128 >= cnt) return;

  // fragment-major A: slot S = rowgroup*64 + kchunk*16 + row, 8 u16 (16B) per slot
  __shared__ u16 As[128 * 32];
  __shared__ int toks[128];
  int tid = threadIdx.x;
  if (tid < 128) {
    int r = mt * 128 + tid; if (r > cnt - 1) r = cnt - 1;
    toks[tid] = ltk[e * LSTR + r] >> 1;
  }
  __syncthreads();

  int lane = tid & 63, wv = tid >> 6;
  int sr = lane & 15, sq = lane >> 4;
  // staging sources: issue0 -> rowgroup wv, issue1 -> rowgroup 4+wv
  long t0 = toks[wv * 16 + sr];
  long t1 = toks[64 + wv * 16 + sr];
  const u16* gA0 = xb + t0 * DIM + sq * 8;
  const u16* gA1 = xb + t1 * DIM + sq * 8;
  u16* dA0 = As + (size_t)tid * 8;
  u16* dA1 = As + (size_t)(256 + tid) * 8;

  int wm = (wv & 1) * 64, wn = (wv >> 1) * 32;
  int lrow = sr, quad = sq;
  int agbase = (wv & 1) * 4;  // rowgroup base for this wave's a-frags

  // direct-global B fragment pointers (lane-resolved)
  long bRow = (long)e * FF + nt * 64 + wn + sr;
  const u16* pG0 = wgb + bRow * DIM + sq * 8;
  const u16* pG1 = pG0 + 16l * DIM;
  const u16* pU0 = wub + bRow * DIM + sq * 8;
  const u16* pU1 = pU0 + 16l * DIM;

  f4v zero = {0.f, 0.f, 0.f, 0.f};
  f4v accg[4][2], accu[4][2];
#pragma unroll
  for (int i = 0; i < 4; i++)
#pragma unroll
    for (int j = 0; j < 2; j++) { accg[i][j] = zero; accu[i][j] = zero; }

  s8v cg0 = *(const s8v*)(pG0);
  s8v cg1 = *(const s8v*)(pG1);
  s8v cu0 = *(const s8v*)(pU0);
  s8v cu1 = *(const s8v*)(pU1);

#pragma unroll 2
  for (int kt = 0; kt < DIM / 32; kt++) {
    int ko = kt * 32;
    __syncthreads();
    glds16(gA0 + ko, dA0);
    glds16(gA1 + ko, dA1);
    int k2 = (ko + 32 < DIM) ? (ko + 32) : ko;  // prefetch next (clamped)
    s8v ng0 = *(const s8v*)(pG0 + k2);
    s8v ng1 = *(const s8v*)(pG1 + k2);
    s8v nu0 = *(const s8v*)(pU0 + k2);
    s8v nu1 = *(const s8v*)(pU1 + k2);
    __syncthreads();
    s8v a[4];
#pragma unroll
    for (int i = 0; i < 4; i++)
      a[i] = *(const s8v*)&As[(agbase + i) * 512 + lane * 8];
#pragma unroll
    for (int i = 0; i < 4; i++) {
      accg[i][0] = __builtin_amdgcn_mfma_f32_16x16x32_bf16(a[i], cg0, accg[i][0], 0, 0, 0);
      accg[i][1] = __builtin_amdgcn_mfma_f32_16x16x32_bf16(a[i], cg1, accg[i][1], 0, 0, 0);
      accu[i][0] = __builtin_amdgcn_mfma_f32_16x16x32_bf16(a[i], cu0, accu[i][0], 0, 0, 0);
      accu[i][1] = __builtin_amdgcn_mfma_f32_16x16x32_bf16(a[i], cu1, accu[i][1], 0, 0, 0);
    }
    cg0 = ng0; cg1 = ng1; cu0 = nu0; cu1 = nu1;
  }
  long hb = (long)baserow[e] + (long)mt * 128;
#pragma unroll
  for (int i = 0; i < 4; i++) {
#pragma unroll
    for (int r = 0; r < 4; r++) {
      int m = wm + i * 16 + quad * 4 + r;
      if (mt * 128 + m < cnt) {
#pragma unroll
        for (int j = 0; j < 2; j++) {
          float gv = accg[i][j][r], uv = accu[i][j][r];
          float h = gv / (1.f + __expf(-gv)) * uv;
          H[(hb + m) * FF + nt * 64 + wn + j * 16 + lrow] = f2bf(h);
        }
      }
    }
  }
}

// ---------------- GEMM2: out += (H @ wo^T) * w ----------------
// H staged in LDS fragment-major; wo frags direct global->VGPR.
__global__ __launch_bounds__(256, 2) void gemm2_kernel(
    const u16* __restrict__ H, const u16* __restrict__ wob,
    float* __restrict__ out, const int* __restrict__ counts, const int* __restrict__ baserow,
    const int* __restrict__ ltk, const float* __restrict__ lw) {
  int id = blockIdx.x;
  int xcd = id & 7;
  int q = id >> 3;        // [0, 120)
  int gg = q / 6;         // [0, 20)
  int nt = q - gg * 6;    // [0, 6)
  int g = gg * 8 + xcd;   // [0, 160)
  int e = g / MAXMT;
  int mt = g - e * MAXMT;
  int cnt = counts[e];
  if (mt * 128 >= cnt) return;

  __shared__ u16 As[128 * 32];
  __shared__ int stok[128];
  __shared__ float sw[128];
  int tid = threadIdx.x;
  if (tid < 128) {
    int r = mt * 128 + tid; if (r > cnt - 1) r = cnt - 1;
    stok[tid] = ltk[e * LSTR + r];
    sw[tid] = lw[e * LSTR + r];
  }
  __syncthreads();
  long hb = (long)baserow[e] + (long)mt * 128;
  int lane = tid & 63, wv = tid >> 6;
  int sr = lane & 15, sq = lane >> 4;
  const u16* gA0 = H + (hb + wv * 16 + sr) * FF + sq * 8;
  const u16* gA1 = H + (hb + 64 + wv * 16 + sr) * FF + sq * 8;
  u16* dA0 = As + (size_t)tid * 8;
  u16* dA1 = As + (size_t)(256 + tid) * 8;

  int wm = (wv & 1) * 64, wn = (wv >> 1) * 64;
  int lrow = sr, quad = sq;
  int agbase = (wv & 1) * 4;

  long bRow = (long)e * DIM + nt * 128 + wn + sr;
  const u16* pB0 = wob + bRow * FF + sq * 8;
  const u16* pB1 = pB0 + 16l * FF;
  const u16* pB2 = pB0 + 32l * FF;
  const u16* pB3 = pB0 + 48l * FF;

  f4v zero = {0.f, 0.f, 0.f, 0.f};
  f4v acc[4][4];
#pragma unroll
  for (int i = 0; i < 4; i++)
#pragma unroll
    for (int j = 0; j < 4; j++) acc[i][j] = zero;

  s8v cb0 = *(const s8v*)(pB0);
  s8v cb1 = *(const s8v*)(pB1);
  s8v cb2 = *(const s8v*)(pB2);
  s8v cb3 = *(const s8v*)(pB3);

#pragma unroll 2
  for (int kt = 0; kt < FF / 32; kt++) {
    int ko = kt * 32;
    __syncthreads();
    glds16(gA0 + ko, dA0);
    glds16(gA1 + ko, dA1);
    int k2 = (ko + 32 < FF) ? (ko + 32) : ko;
    s8v nb0 = *(const s8v*)(pB0 + k2);
    s8v nb1 = *(const s8v*)(pB1 + k2);
    s8v nb2 = *(const s8v*)(pB2 + k2);
    s8v nb3 = *(const s8v*)(pB3 + k2);
    __syncthreads();
    s8v a[4];
#pragma unroll
    for (int i = 0; i < 4; i++)
      a[i] = *(const s8v*)&As[(agbase + i) * 512 + lane * 8];
#pragma unroll
    for (int i = 0; i < 4; i++) {
      acc[i][0] = __builtin_amdgcn_mfma_f32_16x16x32_bf16(a[i], cb0, acc[i][0], 0, 0, 0);
      acc[i][1] = __builtin_amdgcn_mfma_f32_16x16x32_bf16(a[i], cb1, acc[i][1], 0, 0, 0);
      acc[i][2] = __builtin_amdgcn_mfma_f32_16x16x32_bf16(a[i], cb2, acc[i][2], 0, 0, 0);
      acc[i][3] = __builtin_amdgcn_mfma_f32_16x16x32_bf16(a[i], cb3, acc[i][3], 0, 0, 0);
    }
    cb0 = nb0; cb1 = nb1; cb2 = nb2; cb3 = nb3;
  }
#pragma unroll
  for (int i = 0; i < 4; i++) {
#pragma unroll
    for (int r = 0; r < 4; r++) {
      int m = wm + i * 16 + quad * 4 + r;
      if (mt * 128 + m < cnt) {
        int entry = stok[m];
        int t = entry >> 1;
        float w = sw[m];
        long ob = (long)t * DIM + nt * 128;
#pragma unroll
        for (int j = 0; j < 4; j++)
          atomicAdd(&out[ob + wn + j * 16 + lrow], acc[i][j][r] * w);
      }
    }
  }
}

// ---------------- aux loss ----------------
__global__ void aux_kernel(const int* __restrict__ fcnt, const float* __restrict__ psum,
                           const float* __restrict__ zsum, float* __restrict__ outaux) {
  if (threadIdx.x == 0 && blockIdx.x == 0) {
    float lb = 0.f;
    for (int e = 0; e < 8; e++)
      lb += ((float)fcnt[e] / (float)(T_TOK * 2)) * (psum[e] / (float)T_TOK);
    lb *= 8.f;
    float z = zsum[0] / (float)T_TOK;
    outaux[0] = 0.01f * lb + 0.001f * z;
  }
}

extern "C" void kernel_launch(void* const* d_in, const int* in_sizes, int n_in,
                              void* d_out, int out_size, void* d_ws, size_t ws_size,
                              hipStream_t stream) {
  const float* x = (const float*)d_in[0];
  const float* wgate = (const float*)d_in[1];
  const float* wig = (const float*)d_in[2];
  const float* wiu = (const float*)d_in[3];
  const float* wo = (const float*)d_in[4];
  float* out = (float*)d_out;

  char* ws = (char*)d_ws;
  size_t off = 0;
  auto alloc = [&](size_t bytes) {
    void* p = ws + off;
    off += (bytes + 255) & ~(size_t)255;
    return p;
  };
  int* ctrl = (int*)alloc(256);
  u16* xb = (u16*)alloc((size_t)T_TOK * DIM * 2);
  u16* wgb = (u16*)alloc((size_t)NE * FF * DIM * 2);
  u16* wub = (u16*)alloc((size_t)NE * FF * DIM * 2);
  u16* wob = (u16*)alloc((size_t)NE * DIM * FF * 2);
  u16* Hbuf = (u16*)alloc((size_t)(T_TOK * 2 + 128) * FF * 2);
  int* tki = (int*)alloc((size_t)T_TOK * 2 * 4);
  float* tkp = (float*)alloc((size_t)T_TOK * 2 * 4);
  int* ltk = (int*)alloc((size_t)NE * LSTR * 4);
  float* lw = (float*)alloc((size_t)NE * LSTR * 4);
  float* probs = (float*)alloc((size_t)T_TOK * 8 * 4);
  float* lse2 = (float*)alloc((size_t)T_TOK * 4);

  int* fcnt = ctrl;
  int* counts = ctrl + 8;
  int* baserow = ctrl + 16;
  float* psum = (float*)(ctrl + 24);
  float* zsum = (float*)(ctrl + 32);

  hipMemsetAsync(ctrl, 0, 256, stream);
  hipMemsetAsync(out, 0, (size_t)out_size * 4, stream);
  cast_bf16_kernel<<<T_TOK * DIM / 8 / 256, 256, 0, stream>>>(x, xb, T_TOK * DIM / 8);
  cast3_bf16_kernel<<<dim3(NE * FF * DIM / 8 / 256, 3), 256, 0, stream>>>(
      wig, wiu, wo, wgb, wub, wob, NE * FF * DIM / 8);
  router_kernel<<<T_TOK / 4, 256, 0, stream>>>(x, wgate, tki, tkp, probs, lse2);
  reduce_router_kernel<<<T_TOK / 1024, 1024, 0, stream>>>(tki, probs, lse2, fcnt, psum, zsum);
  rank_dispatch_kernel<<<1, 1024, 0, stream>>>(tki, tkp, ltk, lw, counts, baserow);
  gemm1_kernel<<<8 * 48 * MAXMT, 256, 0, stream>>>(xb, wgb, wub, Hbuf, counts, baserow, ltk);
  gemm2_kernel<<<8 * MAXMT * 6, 256, 0, stream>>>(Hbuf, wob, out, counts, baserow, ltk, lw);
  aux_kernel<<<1, 64, 0, stream>>>(fcnt, psum, zsum, out + (size_t)T_TOK * DIM);
}